// Round 1
// baseline (933.364 us; speedup 1.0000x reference)
//
#include <hip/hip_runtime.h>

#define NB 32768
#define NN 12
#define DD 64
#define OBSD 28
#define SUB 8
#define BLOCK 512

__device__ __forceinline__ float tanh_fast(float x) {
    // tanh(x) = 1 - 2/(e^{2x}+1); saturates correctly for |x| large (inf -> 1, 0 -> -1)
    float e = __expf(2.f * x);
    return 1.f - 2.f / (e + 1.f);
}

__global__ __launch_bounds__(BLOCK) void nervenet_fwd(
    const float* __restrict__ obs,
    const float* __restrict__ adjn,
    const float* __restrict__ w_in_t, const float* __restrict__ b_in_t,
    const float* __restrict__ w_in_j, const float* __restrict__ b_in_j,
    const float* __restrict__ w_gp1, const float* __restrict__ b_gp1,
    const float* __restrict__ w_gp2, const float* __restrict__ b_gp2,
    const float* __restrict__ w_gv1, const float* __restrict__ b_gv1,
    const float* __restrict__ w_gv2, const float* __restrict__ b_gv2,
    const float* __restrict__ w_pol1, const float* __restrict__ b_pol1,
    const float* __restrict__ w_pol2, const float* __restrict__ b_pol2,
    const float* __restrict__ w_val1, const float* __restrict__ b_val1,
    const float* __restrict__ w_val2, const float* __restrict__ b_val2,
    float* __restrict__ out)
{
    // xb[buf][sub][node][feat]; each wave (= sub s) touches only its own [s] slice,
    // so the whole layer pipeline needs no __syncthreads.
    __shared__ float xb[2][SUB][NN][DD];
    __shared__ float obs_s[SUB][OBSD];
    __shared__ float adj_s[NN][NN];

    const int tid = threadIdx.x;
    const int d = tid & 63;          // feature lane
    const int s = tid >> 6;          // sub-batch element == wave id
    const int b = blockIdx.x * SUB + s;

    // stage observations (8 rows x 28 = 224 contiguous floats) + adjacency
    if (tid < SUB * OBSD) ((float*)obs_s)[tid] = obs[blockIdx.x * (SUB * OBSD) + tid];
    if (tid >= 256 && tid < 256 + NN * NN) ((float*)adj_s)[tid - 256] = adjn[tid - 256];
    __syncthreads();

    // ---------------- input embedding -> xb[0] ----------------
    {
        float acc = b_in_t[d];
        #pragma unroll
        for (int f = 0; f < 6; ++f) acc += obs_s[s][f] * w_in_t[f * DD + d];
        xb[0][s][0][d] = tanh_fast(acc);

        const float wj0 = w_in_j[d], wj1 = w_in_j[DD + d], bj = b_in_j[d];
        #pragma unroll
        for (int n = 1; n < NN; ++n) {
            float o0 = obs_s[s][4 + 2 * n];      // 6 + 2*(n-1)
            float o1 = obs_s[s][5 + 2 * n];
            xb[0][s][n][d] = tanh_fast(o0 * wj0 + o1 * wj1 + bj);
        }
    }

    // ---------------- one GCN layer: dst = tanh(A @ (src @ W) + bias) ----------------
    auto gcn = [&](const float (*src)[DD], float (*dst)[DD],
                   const float* __restrict__ W, const float* __restrict__ bias) {
        float t[NN];
        #pragma unroll
        for (int m = 0; m < NN; ++m) t[m] = 0.f;

        #pragma unroll
        for (int kc = 0; kc < DD / 16; ++kc) {
            float wc[16];
            #pragma unroll
            for (int kk = 0; kk < 16; ++kk) wc[kk] = W[(kc * 16 + kk) * DD + d]; // coalesced
            #pragma unroll
            for (int m = 0; m < NN; ++m) {
                const float4* xp4 = (const float4*)&src[m][kc * 16];  // LDS broadcast b128
                float4 a0 = xp4[0], a1 = xp4[1], a2 = xp4[2], a3 = xp4[3];
                t[m] += a0.x*wc[0]  + a0.y*wc[1]  + a0.z*wc[2]  + a0.w*wc[3]
                      + a1.x*wc[4]  + a1.y*wc[5]  + a1.z*wc[6]  + a1.w*wc[7]
                      + a2.x*wc[8]  + a2.y*wc[9]  + a2.z*wc[10] + a2.w*wc[11]
                      + a3.x*wc[12] + a3.y*wc[13] + a3.z*wc[14] + a3.w*wc[15];
            }
        }
        const float bd = bias[d];
        #pragma unroll
        for (int n = 0; n < NN; ++n) {
            const float4* ar = (const float4*)&adj_s[n][0];   // 48B rows, 16B aligned
            float4 A0 = ar[0], A1 = ar[1], A2 = ar[2];
            float acc = bd
                + A0.x*t[0] + A0.y*t[1] + A0.z*t[2]  + A0.w*t[3]
                + A1.x*t[4] + A1.y*t[5] + A1.z*t[6]  + A1.w*t[7]
                + A2.x*t[8] + A2.y*t[9] + A2.z*t[10] + A2.w*t[11];
            dst[n][d] = tanh_fast(acc);   // all reads already in regs -> in-place safe
        }
    };

    gcn(xb[0][s], xb[1][s], w_gp1, b_gp1);   // xp1 -> buf1
    gcn(xb[0][s], xb[0][s], w_gv1, b_gv1);   // xv1 -> buf0 (in-place)
    gcn(xb[1][s], xb[1][s], w_gp2, b_gp2);   // xp2 -> buf1 (in-place)
    gcn(xb[0][s], xb[0][s], w_gv2, b_gv2);   // xv2 -> buf0 (in-place)

    // ---------------- policy head: nodes 1..11 of xp2 (buf1) ----------------
    {
        const float bp  = b_pol1[d];
        const float wp2 = w_pol2[d];
        const float bp2 = b_pol2[0];

        float acc[NN - 1];
        #pragma unroll
        for (int nj = 0; nj < NN - 1; ++nj) acc[nj] = bp;

        #pragma unroll
        for (int kc = 0; kc < DD / 16; ++kc) {
            float wc[16];
            #pragma unroll
            for (int kk = 0; kk < 16; ++kk) wc[kk] = w_pol1[(kc * 16 + kk) * DD + d];
            #pragma unroll
            for (int nj = 0; nj < NN - 1; ++nj) {
                const float4* xp4 = (const float4*)&xb[1][s][nj + 1][kc * 16];
                float4 a0 = xp4[0], a1 = xp4[1], a2 = xp4[2], a3 = xp4[3];
                acc[nj] += a0.x*wc[0]  + a0.y*wc[1]  + a0.z*wc[2]  + a0.w*wc[3]
                         + a1.x*wc[4]  + a1.y*wc[5]  + a1.z*wc[6]  + a1.w*wc[7]
                         + a2.x*wc[8]  + a2.y*wc[9]  + a2.z*wc[10] + a2.w*wc[11]
                         + a3.x*wc[12] + a3.y*wc[13] + a3.z*wc[14] + a3.w*wc[15];
            }
        }

        float myout = 0.f;
        #pragma unroll
        for (int nj = 0; nj < NN - 1; ++nj) {
            float p = tanh_fast(acc[nj]) * wp2;
            #pragma unroll
            for (int off = 32; off; off >>= 1) p += __shfl_xor(p, off);
            if (d == nj) myout = p + bp2;
        }
        if (d < 11) out[b * 11 + d] = myout;
    }

    // ---------------- value head: flat xv2 (buf0, 768 contiguous) ----------------
    {
        float acc = b_val1[d];
        const float* xf = &xb[0][s][0][0];
        #pragma unroll 8
        for (int j4 = 0; j4 < (NN * DD) / 4; ++j4) {
            float4 a = *(const float4*)&xf[4 * j4];
            const float* wp = &w_val1[(4 * j4) * DD + d];   // coalesced per row
            acc += a.x * wp[0] + a.y * wp[DD] + a.z * wp[2 * DD] + a.w * wp[3 * DD];
        }
        float hv = tanh_fast(acc);
        float pv = hv * w_val2[d];
        #pragma unroll
        for (int off = 32; off; off >>= 1) pv += __shfl_xor(pv, off);
        if (d == 11) out[11 * NB + b] = pv + b_val2[0];
    }
}

extern "C" void kernel_launch(void* const* d_in, const int* in_sizes, int n_in,
                              void* d_out, int out_size, void* d_ws, size_t ws_size,
                              hipStream_t stream) {
    (void)in_sizes; (void)n_in; (void)d_ws; (void)ws_size; (void)out_size;
    const float** p = (const float**)d_in;
    dim3 grid(NB / SUB), block(BLOCK);
    hipLaunchKernelGGL(nervenet_fwd, grid, block, 0, stream,
        p[0], p[1], p[2], p[3], p[4], p[5], p[6], p[7], p[8], p[9], p[10],
        p[11], p[12], p[13], p[14], p[15], p[16], p[17], p[18], p[19], p[20], p[21],
        (float*)d_out);
}

// Round 2
// 109.344 us; speedup vs baseline: 8.5360x; 8.5360x over previous
//
#include <hip/hip_runtime.h>

#define NB 32768
#define NN 12
#define DD 64
#define OBSD 28
#define EPB 16            // batch elements per block (one MFMA N-tile)
#define NSLOT 136         // weight-fragment slots in d_ws

typedef __bf16 bf16x8 __attribute__((ext_vector_type(8)));
typedef __bf16 bf16x4 __attribute__((ext_vector_type(4)));
typedef float  f32x4  __attribute__((ext_vector_type(4)));

#define MFMA(a, b, c) __builtin_amdgcn_mfma_f32_16x16x32_bf16((a), (b), (c), 0, 0, 0)

__device__ __forceinline__ float tanh_fast(float x) {
    float e = __expf(2.f * x);
    return 1.f - 2.f / (e + 1.f);
}

// adjacency sparsity (12 nodes, 11 edges + self loops = 34 nonzeros), grouped by output node
static constexpr int AC_OFF[13] = {0,5,8,11,13,16,19,21,24,27,29,32,34};
static constexpr int AC_M[34] = {0,1,4,7,10, 0,1,2, 1,2,3, 2,3, 0,4,5, 4,5,6, 5,6, 0,7,8, 7,8,9, 8,9, 0,10,11, 10,11};
static constexpr int AC_N[34] = {0,0,0,0,0, 1,1,1, 2,2,2, 3,3, 4,4,4, 5,5,5, 6,6, 7,7,7, 8,8,8, 9,9, 10,10,10, 11,11};

// ---------------------------------------------------------------------------
// prep: pack W^T into MFMA A-fragment layout, bf16, into d_ws.
// slot map: 0..31 gcn {gp1,gp2,gv1,gv2}: mat*8 + w*2 + ks
//           32..39 pol1: 32 + w*2 + ks
//           40..135 val1: 40 + w*24 + ks   (K=768 -> 24 ksteps)
// per (slot, lane): 8 bf16 = A[w*16 + (l&15)][ks*32 + (l>>4)*8 + i] = W[k][dout]
// ---------------------------------------------------------------------------
__global__ __launch_bounds__(256) void prep_weights(
    const float* __restrict__ gp1, const float* __restrict__ gp2,
    const float* __restrict__ gv1, const float* __restrict__ gv2,
    const float* __restrict__ pol1, const float* __restrict__ val1,
    __bf16* __restrict__ wsb)
{
    int gid = blockIdx.x * blockDim.x + threadIdx.x;
    if (gid >= NSLOT * 64) return;
    int slot = gid >> 6, l = gid & 63;
    const float* W; int w, ks;
    if (slot < 32) {
        int m = slot >> 3;
        W = (m == 0) ? gp1 : (m == 1) ? gp2 : (m == 2) ? gv1 : gv2;
        w = (slot >> 1) & 3; ks = slot & 1;
    } else if (slot < 40) {
        W = pol1; w = (slot - 32) >> 1; ks = slot & 1;
    } else {
        int idx = slot - 40; W = val1; w = idx / 24; ks = idx % 24;
    }
    int dout = w * 16 + (l & 15);
    int k0 = ks * 32 + (l >> 4) * 8;
    bf16x8 v;
    #pragma unroll
    for (int i = 0; i < 8; ++i) v[i] = (__bf16)W[(size_t)(k0 + i) * 64 + dout];
    *(bf16x8*)(wsb + (size_t)gid * 8) = v;
}

// ---------------------------------------------------------------------------
// main kernel: 256 threads = 4 waves (wave w owns out-feature tile w), 16 elements
// ---------------------------------------------------------------------------
__global__ __launch_bounds__(256, 3) void nervenet_mfma(
    const float* __restrict__ obs, const float* __restrict__ adjn,
    const float* __restrict__ w_in_t, const float* __restrict__ b_in_t,
    const float* __restrict__ w_in_j, const float* __restrict__ b_in_j,
    const float* __restrict__ b_gp1, const float* __restrict__ b_gp2,
    const float* __restrict__ b_gv1, const float* __restrict__ b_gv2,
    const float* __restrict__ b_pol1, const float* __restrict__ w_pol2, const float* __restrict__ b_pol2,
    const float* __restrict__ b_val1, const float* __restrict__ w_val2, const float* __restrict__ b_val2,
    const __bf16* __restrict__ wsb, float* __restrict__ out)
{
    // x buffers: [node][el][feat] bf16, rows 128 B, XOR-swizzled by (el&7)<<4
    __shared__ unsigned char xb0[NN * EPB * DD * 2];   // 24576
    __shared__ unsigned char xb1[NN * EPB * DD * 2];   // 24576
    __shared__ float scratch[768];                     // obs staging, later head partials

    const int tid = threadIdx.x;
    const int l   = tid & 63;
    const int el  = l & 15;
    const int kg  = l >> 4;
    const int w   = tid >> 6;
    const int b0  = blockIdx.x * EPB;
    const int swz = (el & 7) << 4;

    // adjacency coefficients: wave-uniform -> scalar loads, live in SGPRs
    float ac[34];
    #pragma unroll
    for (int i = 0; i < 34; ++i) ac[i] = adjn[AC_N[i] * 12 + AC_M[i]];

    // ---- P0: stage obs + input embedding -> xb0 ----
    for (int i = tid; i < EPB * OBSD; i += 256) scratch[i] = obs[(size_t)b0 * OBSD + i];
    __syncthreads();
    {
        const int ee = tid & 15, fg = tid >> 4;       // feats fg*4 .. fg*4+3
        const float* os = &scratch[ee * OBSD];
        const int eswz = (ee & 7) << 4;
        f32x4 y = *(const f32x4*)(b_in_t + fg * 4);
        #pragma unroll
        for (int ff = 0; ff < 6; ++ff) {
            f32x4 wv = *(const f32x4*)(w_in_t + ff * DD + fg * 4);
            float o = os[ff];
            #pragma unroll
            for (int r = 0; r < 4; ++r) y[r] += o * wv[r];
        }
        bf16x4 ov;
        #pragma unroll
        for (int r = 0; r < 4; ++r) ov[r] = (__bf16)tanh_fast(y[r]);
        *(bf16x4*)(&xb0[(0 * EPB + ee) * 128 + ((fg * 8) ^ eswz)]) = ov;

        f32x4 wj0 = *(const f32x4*)(w_in_j + fg * 4);
        f32x4 wj1 = *(const f32x4*)(w_in_j + DD + fg * 4);
        f32x4 bj  = *(const f32x4*)(b_in_j + fg * 4);
        #pragma unroll
        for (int n = 1; n < NN; ++n) {
            float o0 = os[4 + 2 * n], o1 = os[5 + 2 * n];
            #pragma unroll
            for (int r = 0; r < 4; ++r) y[r] = bj[r] + o0 * wj0[r] + o1 * wj1[r];
            #pragma unroll
            for (int r = 0; r < 4; ++r) ov[r] = (__bf16)tanh_fast(y[r]);
            *(bf16x4*)(&xb0[(n * EPB + ee) * 128 + ((fg * 8) ^ eswz)]) = ov;
        }
    }
    __syncthreads();

    auto rdfrag = [&](const unsigned char* buf, int n, int ks) {
        return *(const bf16x8*)(buf + (n * EPB + el) * 128 + ((ks * 64 + kg * 16) ^ swz));
    };
    auto ldws = [&](int slot) {
        return *(const bf16x8*)(wsb + ((size_t)slot * 64 + l) * 8);
    };

    f32x4 acc[NN];

    auto gcn_read = [&](const unsigned char* src, int slotbase) {
        bf16x8 wf0 = ldws(slotbase + w * 2 + 0);
        bf16x8 wf1 = ldws(slotbase + w * 2 + 1);
        #pragma unroll
        for (int n = 0; n < NN; ++n) {
            bf16x8 x0 = rdfrag(src, n, 0);
            bf16x8 x1 = rdfrag(src, n, 1);
            f32x4 a = {0.f, 0.f, 0.f, 0.f};
            a = MFMA(wf0, x0, a);
            a = MFMA(wf1, x1, a);
            acc[n] = a;
        }
    };
    auto gcn_write = [&](unsigned char* dst, const float* bias) {
        f32x4 bv = *(const f32x4*)(bias + w * 16 + kg * 4);
        #pragma unroll
        for (int n = 0; n < NN; ++n) {
            f32x4 y;
            #pragma unroll
            for (int r = 0; r < 4; ++r) y[r] = bv[r];
            #pragma unroll
            for (int j = AC_OFF[n]; j < AC_OFF[n + 1]; ++j) {
                const float a = ac[j];
                #pragma unroll
                for (int r = 0; r < 4; ++r) y[r] += a * acc[AC_M[j]][r];
            }
            bf16x4 o;
            #pragma unroll
            for (int r = 0; r < 4; ++r) o[r] = (__bf16)tanh_fast(y[r]);
            *(bf16x4*)(dst + (n * EPB + el) * 128 + (((w * 16 + kg * 4) * 2) ^ swz)) = o;
        }
    };

    // gp1: xb0 -> xb1  (distinct buffers, no extra barrier needed before write)
    gcn_read(xb0, 0);
    gcn_write(xb1, b_gp1);
    // gv1: xb0 -> xb0 in place (reads, barrier, writes)
    gcn_read(xb0, 16);
    __syncthreads();
    gcn_write(xb0, b_gv1);
    __syncthreads();
    // gp2: xb1 -> xb1 in place
    gcn_read(xb1, 8);
    __syncthreads();
    gcn_write(xb1, b_gp2);
    __syncthreads();
    // gv2: xb0 -> xb0 in place
    gcn_read(xb0, 24);
    __syncthreads();
    gcn_write(xb0, b_gv2);
    __syncthreads();

    // ---- heads: policy reads xb1 (xp2), value reads xb0 (xv2) ----
    {
        f32x4 bp  = *(const f32x4*)(b_pol1 + w * 16 + kg * 4);
        f32x4 wp2 = *(const f32x4*)(w_pol2 + w * 16 + kg * 4);
        bf16x8 pf0 = ldws(32 + w * 2 + 0);
        bf16x8 pf1 = ldws(32 + w * 2 + 1);
        #pragma unroll
        for (int nj = 0; nj < 11; ++nj) {
            bf16x8 x0 = rdfrag(xb1, nj + 1, 0);
            bf16x8 x1 = rdfrag(xb1, nj + 1, 1);
            f32x4 a = bp;
            a = MFMA(pf0, x0, a);
            a = MFMA(pf1, x1, a);
            float p = 0.f;
            #pragma unroll
            for (int r = 0; r < 4; ++r) p += tanh_fast(a[r]) * wp2[r];
            p += __shfl_xor(p, 16);
            p += __shfl_xor(p, 32);
            if (kg == 0) scratch[w * 176 + nj * 16 + el] = p;
        }

        f32x4 a0 = *(const f32x4*)(b_val1 + w * 16 + kg * 4);
        f32x4 a1 = {0.f, 0.f, 0.f, 0.f};
        #pragma unroll 4
        for (int ks = 0; ks < 24; ks += 2) {
            bf16x8 wf0 = ldws(40 + w * 24 + ks);
            bf16x8 wf1 = ldws(40 + w * 24 + ks + 1);
            int n = ks >> 1;
            bf16x8 xf0 = *(const bf16x8*)(xb0 + (n * EPB + el) * 128 + ((kg * 16) ^ swz));
            bf16x8 xf1 = *(const bf16x8*)(xb0 + (n * EPB + el) * 128 + ((64 + kg * 16) ^ swz));
            a0 = MFMA(wf0, xf0, a0);
            a1 = MFMA(wf1, xf1, a1);
        }
        f32x4 wv2 = *(const f32x4*)(w_val2 + w * 16 + kg * 4);
        float p = 0.f;
        #pragma unroll
        for (int r = 0; r < 4; ++r) p += tanh_fast(a0[r] + a1[r]) * wv2[r];
        p += __shfl_xor(p, 16);
        p += __shfl_xor(p, 32);
        if (kg == 0) scratch[704 + w * 16 + el] = p;
    }
    __syncthreads();

    if (tid < 176) {
        int e2 = tid / 11, nj = tid - e2 * 11;
        out[(size_t)b0 * 11 + tid] =
            scratch[nj * 16 + e2] + scratch[176 + nj * 16 + e2] +
            scratch[352 + nj * 16 + e2] + scratch[528 + nj * 16 + e2] + b_pol2[0];
    }
    if (tid >= 192 && tid < 192 + EPB) {
        int e2 = tid - 192;
        out[(size_t)NB * 11 + b0 + e2] =
            scratch[704 + e2] + scratch[720 + e2] + scratch[736 + e2] + scratch[752 + e2] + b_val2[0];
    }
}

extern "C" void kernel_launch(void* const* d_in, const int* in_sizes, int n_in,
                              void* d_out, int out_size, void* d_ws, size_t ws_size,
                              hipStream_t stream) {
    (void)in_sizes; (void)n_in; (void)out_size; (void)ws_size;
    const float** p = (const float**)d_in;
    __bf16* wsb = (__bf16*)d_ws;
    hipLaunchKernelGGL(prep_weights, dim3(34), dim3(256), 0, stream,
        p[6], p[8], p[10], p[12], p[14], p[18], wsb);
    hipLaunchKernelGGL(nervenet_mfma, dim3(NB / EPB), dim3(256), 0, stream,
        p[0], p[1], p[2], p[3], p[4], p[5],
        p[7], p[9], p[11], p[13],
        p[15], p[16], p[17],
        p[19], p[20], p[21],
        wsb, (float*)d_out);
}

// Round 3
// 77.579 us; speedup vs baseline: 12.0311x; 1.4095x over previous
//
#include <hip/hip_runtime.h>

#define NB 32768
#define NN 12
#define DD 64
#define OBSD 28
#define EPB 16            // batch elements per block (one MFMA N-tile)
#define NSLOT 136         // weight-fragment slots in d_ws

typedef __bf16 bf16x8 __attribute__((ext_vector_type(8)));
typedef __bf16 bf16x4 __attribute__((ext_vector_type(4)));
typedef float  f32x4  __attribute__((ext_vector_type(4)));

#define MFMA(a, b, c) __builtin_amdgcn_mfma_f32_16x16x32_bf16((a), (b), (c), 0, 0, 0)

__device__ __forceinline__ float tanh_fast(float x) {
    // tanh(x) = 1 - 2/(e^{2x}+1);  e^{2x} = 2^(x*2/ln2).  5 VALU insts, no div.
    float e = __builtin_amdgcn_exp2f(x * 2.885390081777927f);
    float r = __builtin_amdgcn_rcpf(e + 1.f);
    return __builtin_fmaf(-2.f, r, 1.f);
}

// adjacency sparsity (12 nodes, 11 edges + self loops = 34 nonzeros), grouped by output node
static constexpr int AC_OFF[13] = {0,5,8,11,13,16,19,21,24,27,29,32,34};
static constexpr int AC_M[34] = {0,1,4,7,10, 0,1,2, 1,2,3, 2,3, 0,4,5, 4,5,6, 5,6, 0,7,8, 7,8,9, 8,9, 0,10,11, 10,11};
static constexpr int AC_N[34] = {0,0,0,0,0, 1,1,1, 2,2,2, 3,3, 4,4,4, 5,5,5, 6,6, 7,7,7, 8,8,8, 9,9, 10,10,10, 11,11};

// ---------------------------------------------------------------------------
// prep: pack W^T into MFMA A-fragment layout, bf16, into d_ws.
// slot map: 0..31 gcn {gp1,gp2,gv1,gv2}: mat*8 + w*2 + ks
//           32..39 pol1: 32 + w*2 + ks
//           40..135 val1: 40 + w*24 + ks   (K=768 -> 24 ksteps)
// per (slot, lane): 8 bf16 = A[w*16 + (l&15)][ks*32 + (l>>4)*8 + i] = W[k][dout]
// ---------------------------------------------------------------------------
__global__ __launch_bounds__(256) void prep_weights(
    const float* __restrict__ gp1, const float* __restrict__ gp2,
    const float* __restrict__ gv1, const float* __restrict__ gv2,
    const float* __restrict__ pol1, const float* __restrict__ val1,
    __bf16* __restrict__ wsb)
{
    int gid = blockIdx.x * blockDim.x + threadIdx.x;
    if (gid >= NSLOT * 64) return;
    int slot = gid >> 6, l = gid & 63;
    const float* W; int w, ks;
    if (slot < 32) {
        int m = slot >> 3;
        W = (m == 0) ? gp1 : (m == 1) ? gp2 : (m == 2) ? gv1 : gv2;
        w = (slot >> 1) & 3; ks = slot & 1;
    } else if (slot < 40) {
        W = pol1; w = (slot - 32) >> 1; ks = slot & 1;
    } else {
        int idx = slot - 40; W = val1; w = idx / 24; ks = idx % 24;
    }
    int dout = w * 16 + (l & 15);
    int k0 = ks * 32 + (l >> 4) * 8;
    bf16x8 v;
    #pragma unroll
    for (int i = 0; i < 8; ++i) v[i] = (__bf16)W[(size_t)(k0 + i) * 64 + dout];
    *(bf16x8*)(wsb + (size_t)gid * 8) = v;
}

// ---------------------------------------------------------------------------
// main kernel: 256 threads = 4 waves (wave w owns out-feature tile w), 16 elements.
// Single 24KB activation buffer; p-branch first, re-embed, then v-branch.
// LDS = 24576 + 1792 + 2816 + 256 = 29440 B -> 5 blocks/CU (20 waves).
// ---------------------------------------------------------------------------
__global__ __launch_bounds__(256, 4) void nervenet_mfma(
    const float* __restrict__ obs, const float* __restrict__ adjn,
    const float* __restrict__ w_in_t, const float* __restrict__ b_in_t,
    const float* __restrict__ w_in_j, const float* __restrict__ b_in_j,
    const float* __restrict__ b_gp1, const float* __restrict__ b_gp2,
    const float* __restrict__ b_gv1, const float* __restrict__ b_gv2,
    const float* __restrict__ b_pol1, const float* __restrict__ w_pol2, const float* __restrict__ b_pol2,
    const float* __restrict__ b_val1, const float* __restrict__ w_val2, const float* __restrict__ b_val2,
    const __bf16* __restrict__ wsb, float* __restrict__ out)
{
    // X: [node][el][feat] bf16, rows 128 B, XOR-swizzled by (el&7)<<4
    __shared__ unsigned char X[NN * EPB * DD * 2];   // 24576
    __shared__ float obs_s[EPB * OBSD];              // 1792 (live until re-embed)
    __shared__ float polp[4 * 11 * EPB];             // 2816 (policy partials)
    __shared__ float valp[4 * EPB];                  // 256  (value partials)

    const int tid = threadIdx.x;
    const int l   = tid & 63;
    const int el  = l & 15;
    const int kg  = l >> 4;
    const int w   = tid >> 6;
    const int b0  = blockIdx.x * EPB;
    const int swz = (el & 7) << 4;

    // adjacency coefficients: wave-uniform indices -> scalar loads (SGPRs)
    float ac[34];
    #pragma unroll
    for (int i = 0; i < 34; ++i) ac[i] = adjn[AC_N[i] * 12 + AC_M[i]];

    // ---- stage obs ----
    for (int i = tid; i < EPB * OBSD; i += 256) obs_s[i] = obs[(size_t)b0 * OBSD + i];
    __syncthreads();

    // ---- input embedding -> X (called twice: before p-branch and before v-branch) ----
    auto embed = [&]() {
        const int ee = tid & 15, fg = tid >> 4;       // feats fg*4 .. fg*4+3
        const float* os = &obs_s[ee * OBSD];
        const int eswz = (ee & 7) << 4;
        f32x4 y = *(const f32x4*)(b_in_t + fg * 4);
        #pragma unroll
        for (int ff = 0; ff < 6; ++ff) {
            f32x4 wv = *(const f32x4*)(w_in_t + ff * DD + fg * 4);
            float o = os[ff];
            #pragma unroll
            for (int r = 0; r < 4; ++r) y[r] += o * wv[r];
        }
        bf16x4 ov;
        #pragma unroll
        for (int r = 0; r < 4; ++r) ov[r] = (__bf16)tanh_fast(y[r]);
        *(bf16x4*)(&X[(0 * EPB + ee) * 128 + ((fg * 8) ^ eswz)]) = ov;

        f32x4 wj0 = *(const f32x4*)(w_in_j + fg * 4);
        f32x4 wj1 = *(const f32x4*)(w_in_j + DD + fg * 4);
        f32x4 bj  = *(const f32x4*)(b_in_j + fg * 4);
        #pragma unroll
        for (int n = 1; n < NN; ++n) {
            float o0 = os[4 + 2 * n], o1 = os[5 + 2 * n];
            f32x4 t;
            #pragma unroll
            for (int r = 0; r < 4; ++r) t[r] = bj[r] + o0 * wj0[r] + o1 * wj1[r];
            #pragma unroll
            for (int r = 0; r < 4; ++r) ov[r] = (__bf16)tanh_fast(t[r]);
            *(bf16x4*)(&X[(n * EPB + ee) * 128 + ((fg * 8) ^ eswz)]) = ov;
        }
    };

    auto rdfrag = [&](int n, int ks) {
        return *(const bf16x8*)(X + (n * EPB + el) * 128 + ((ks * 64 + kg * 16) ^ swz));
    };
    auto ldws = [&](int slot) {
        return *(const bf16x8*)(wsb + ((size_t)slot * 64 + l) * 8);
    };

    f32x4 acc[NN];

    auto gcn_read = [&](int slotbase) {
        bf16x8 wf0 = ldws(slotbase + w * 2 + 0);
        bf16x8 wf1 = ldws(slotbase + w * 2 + 1);
        #pragma unroll
        for (int n = 0; n < NN; ++n) {
            bf16x8 x0 = rdfrag(n, 0);
            bf16x8 x1 = rdfrag(n, 1);
            f32x4 a = {0.f, 0.f, 0.f, 0.f};
            a = MFMA(wf0, x0, a);
            a = MFMA(wf1, x1, a);
            acc[n] = a;
        }
    };
    auto gcn_write = [&](const float* bias) {
        f32x4 bv = *(const f32x4*)(bias + w * 16 + kg * 4);
        #pragma unroll
        for (int n = 0; n < NN; ++n) {
            f32x4 y = bv;
            #pragma unroll
            for (int j = AC_OFF[n]; j < AC_OFF[n + 1]; ++j) {
                const float a = ac[j];
                #pragma unroll
                for (int r = 0; r < 4; ++r) y[r] += a * acc[AC_M[j]][r];
            }
            bf16x4 o;
            #pragma unroll
            for (int r = 0; r < 4; ++r) o[r] = (__bf16)tanh_fast(y[r]);
            *(bf16x4*)(X + (n * EPB + el) * 128 + (((w * 16 + kg * 4) * 2) ^ swz)) = o;
        }
    };

    // ================= policy branch =================
    embed();                 // X = x
    __syncthreads();
    gcn_read(0);             // acc = x @ Wgp1
    __syncthreads();
    gcn_write(b_gp1);        // X = xp1
    __syncthreads();
    gcn_read(8);             // acc = xp1 @ Wgp2
    __syncthreads();
    gcn_write(b_gp2);        // X = xp2
    __syncthreads();

    // policy head -> polp
    {
        f32x4 bp  = *(const f32x4*)(b_pol1 + w * 16 + kg * 4);
        f32x4 wp2 = *(const f32x4*)(w_pol2 + w * 16 + kg * 4);
        bf16x8 pf0 = ldws(32 + w * 2 + 0);
        bf16x8 pf1 = ldws(32 + w * 2 + 1);
        #pragma unroll
        for (int nj = 0; nj < 11; ++nj) {
            bf16x8 x0 = rdfrag(nj + 1, 0);
            bf16x8 x1 = rdfrag(nj + 1, 1);
            f32x4 a = bp;
            a = MFMA(pf0, x0, a);
            a = MFMA(pf1, x1, a);
            float p = 0.f;
            #pragma unroll
            for (int r = 0; r < 4; ++r) p += tanh_fast(a[r]) * wp2[r];
            p += __shfl_xor(p, 16);
            p += __shfl_xor(p, 32);
            if (kg == 0) polp[w * 176 + nj * 16 + el] = p;
        }
    }
    __syncthreads();         // X reads done before re-embed overwrites

    // ================= value branch =================
    embed();                 // X = x again (obs_s still intact)
    __syncthreads();
    gcn_read(16);            // acc = x @ Wgv1
    __syncthreads();
    gcn_write(b_gv1);        // X = xv1
    __syncthreads();
    gcn_read(24);            // acc = xv1 @ Wgv2
    __syncthreads();
    gcn_write(b_gv2);        // X = xv2
    __syncthreads();

    // value head -> valp
    {
        f32x4 a0 = *(const f32x4*)(b_val1 + w * 16 + kg * 4);
        f32x4 a1 = {0.f, 0.f, 0.f, 0.f};
        #pragma unroll 4
        for (int ks = 0; ks < 24; ks += 2) {
            bf16x8 wf0 = ldws(40 + w * 24 + ks);
            bf16x8 wf1 = ldws(40 + w * 24 + ks + 1);
            int n = ks >> 1;
            bf16x8 xf0 = rdfrag(n, 0);
            bf16x8 xf1 = rdfrag(n, 1);
            a0 = MFMA(wf0, xf0, a0);
            a1 = MFMA(wf1, xf1, a1);
        }
        f32x4 wv2 = *(const f32x4*)(w_val2 + w * 16 + kg * 4);
        float p = 0.f;
        #pragma unroll
        for (int r = 0; r < 4; ++r) p += tanh_fast(a0[r] + a1[r]) * wv2[r];
        p += __shfl_xor(p, 16);
        p += __shfl_xor(p, 32);
        if (kg == 0) valp[w * 16 + el] = p;
    }
    __syncthreads();

    // ================= final outputs =================
    if (tid < 176) {
        int e2 = tid / 11, nj = tid - e2 * 11;
        out[(size_t)b0 * 11 + tid] =
            polp[nj * 16 + e2] + polp[176 + nj * 16 + e2] +
            polp[352 + nj * 16 + e2] + polp[528 + nj * 16 + e2] + b_pol2[0];
    }
    if (tid >= 192 && tid < 192 + EPB) {
        int e2 = tid - 192;
        out[(size_t)NB * 11 + b0 + e2] =
            valp[e2] + valp[16 + e2] + valp[32 + e2] + valp[48 + e2] + b_val2[0];
    }
}

extern "C" void kernel_launch(void* const* d_in, const int* in_sizes, int n_in,
                              void* d_out, int out_size, void* d_ws, size_t ws_size,
                              hipStream_t stream) {
    (void)in_sizes; (void)n_in; (void)out_size; (void)ws_size;
    const float** p = (const float**)d_in;
    __bf16* wsb = (__bf16*)d_ws;
    hipLaunchKernelGGL(prep_weights, dim3(34), dim3(256), 0, stream,
        p[6], p[8], p[10], p[12], p[14], p[18], wsb);
    hipLaunchKernelGGL(nervenet_mfma, dim3(NB / EPB), dim3(256), 0, stream,
        p[0], p[1], p[2], p[3], p[4], p[5],
        p[7], p[9], p[11], p[13],
        p[15], p[16], p[17],
        p[19], p[20], p[21],
        wsb, (float*)d_out);
}

// Round 4
// 67.877 us; speedup vs baseline: 13.7507x; 1.1429x over previous
//
#include <hip/hip_runtime.h>

#define NB 32768
#define NN 12
#define DD 64
#define OBSD 28
#define EPB 16            // batch elements per block (one MFMA N-tile)
#define NSLOT 136         // weight-fragment slots in d_ws

typedef __bf16 bf16x8 __attribute__((ext_vector_type(8)));
typedef __bf16 bf16x4 __attribute__((ext_vector_type(4)));
typedef __bf16 bf16x2 __attribute__((ext_vector_type(2)));
typedef float  f32x4  __attribute__((ext_vector_type(4)));

#define MFMA(a, b, c) __builtin_amdgcn_mfma_f32_16x16x32_bf16((a), (b), (c), 0, 0, 0)

__device__ __forceinline__ float tanh_fast(float x) {
    // tanh(x) = 1 - 2/(e^{2x}+1);  e^{2x} = 2^(x*2/ln2).  3 full-rate + 2 trans ops.
    float e = __builtin_amdgcn_exp2f(x * 2.885390081777927f);
    float r = __builtin_amdgcn_rcpf(e + 1.f);
    return __builtin_fmaf(-2.f, r, 1.f);
}

// adjacency sparsity (12 nodes, 11 edges + self loops = 34 nonzeros), grouped by output node
static constexpr int AC_OFF[13] = {0,5,8,11,13,16,19,21,24,27,29,32,34};
static constexpr int AC_M[34] = {0,1,4,7,10, 0,1,2, 1,2,3, 2,3, 0,4,5, 4,5,6, 5,6, 0,7,8, 7,8,9, 8,9, 0,10,11, 10,11};
static constexpr int AC_N[34] = {0,0,0,0,0, 1,1,1, 2,2,2, 3,3, 4,4,4, 5,5,5, 6,6, 7,7,7, 8,8,8, 9,9, 10,10,10, 11,11};

// ---------------------------------------------------------------------------
// prep: pack W^T into MFMA A-fragment layout, bf16, into d_ws.
// slot map: 0..31 gcn {gp1,gp2,gv1,gv2}: mat*8 + w*2 + ks
//           32..39 pol1: 32 + w*2 + ks
//           40..135 val1: 40 + w*24 + ks   (K=768 -> 24 ksteps)
// per (slot, lane): 8 bf16 = A[w*16 + (l&15)][ks*32 + (l>>4)*8 + i] = W[k][dout]
// ---------------------------------------------------------------------------
__global__ __launch_bounds__(256) void prep_weights(
    const float* __restrict__ gp1, const float* __restrict__ gp2,
    const float* __restrict__ gv1, const float* __restrict__ gv2,
    const float* __restrict__ pol1, const float* __restrict__ val1,
    __bf16* __restrict__ wsb)
{
    int gid = blockIdx.x * blockDim.x + threadIdx.x;
    if (gid >= NSLOT * 64) return;
    int slot = gid >> 6, l = gid & 63;
    const float* W; int w, ks;
    if (slot < 32) {
        int m = slot >> 3;
        W = (m == 0) ? gp1 : (m == 1) ? gp2 : (m == 2) ? gv1 : gv2;
        w = (slot >> 1) & 3; ks = slot & 1;
    } else if (slot < 40) {
        W = pol1; w = (slot - 32) >> 1; ks = slot & 1;
    } else {
        int idx = slot - 40; W = val1; w = idx / 24; ks = idx % 24;
    }
    int dout = w * 16 + (l & 15);
    int k0 = ks * 32 + (l >> 4) * 8;
    bf16x8 v;
    #pragma unroll
    for (int i = 0; i < 8; ++i) v[i] = (__bf16)W[(size_t)(k0 + i) * 64 + dout];
    *(bf16x8*)(wsb + (size_t)gid * 8) = v;
}

// ---------------------------------------------------------------------------
// main kernel: 512 threads = 8 waves. Waves 0-3: policy branch (tile w=wv&3),
// waves 4-7: value branch. Staggered 2-buffer schedule, 6 barriers total.
// LDS = 2*24576 + 2816 + 256 = 52224 B -> 3 blocks/CU (24 waves).
// ---------------------------------------------------------------------------
__global__ __launch_bounds__(512, 6) void nervenet_mfma(
    const float* __restrict__ obs, const float* __restrict__ adjn,
    const float* __restrict__ w_in_t, const float* __restrict__ b_in_t,
    const float* __restrict__ w_in_j, const float* __restrict__ b_in_j,
    const float* __restrict__ b_gp1, const float* __restrict__ b_gp2,
    const float* __restrict__ b_gv1, const float* __restrict__ b_gv2,
    const float* __restrict__ b_pol1, const float* __restrict__ w_pol2, const float* __restrict__ b_pol2,
    const float* __restrict__ b_val1, const float* __restrict__ w_val2, const float* __restrict__ b_val2,
    const __bf16* __restrict__ wsb, float* __restrict__ out)
{
    // [node][el][feat] bf16, rows 128 B, XOR-swizzled by (el&7)<<4
    __shared__ unsigned char X [NN * EPB * DD * 2];   // 24576: x -> xv1 -> xv2 (in place)
    __shared__ unsigned char XP[NN * EPB * DD * 2];   // 24576: xp1 -> xp2 (in place)
    __shared__ float polp[4 * 11 * EPB];              // 2816 policy partials
    __shared__ float valp[4 * EPB];                   // 256  value partials

    const int tid = threadIdx.x;
    const int l   = tid & 63;
    const int el  = l & 15;
    const int kg  = l >> 4;
    const int wv  = tid >> 6;        // 0..7
    const int w   = wv & 3;          // out-feature tile within branch
    const bool isP = wv < 4;
    const int b0  = blockIdx.x * EPB;
    const int swz = (el & 7) << 4;

    // adjacency coefficients: literal indices + uniform pointer -> scalar loads
    float ac[34];
    #pragma unroll
    for (int i = 0; i < 34; ++i) ac[i] = adjn[AC_N[i] * 12 + AC_M[i]];

    // ---- embed: all 8 waves, each thread 2 feats x 12 nodes, obs direct from global ----
    {
        const int ee = tid & 15, fg = tid >> 4;       // fg 0..31 -> feats fg*2, fg*2+1
        const int eswz = (ee & 7) << 4;
        const float* os = obs + (size_t)(b0 + ee) * OBSD;   // 112B rows, 16B-aligned
        f32x4 o0 = *(const f32x4*)(os);
        f32x4 o1 = *(const f32x4*)(os + 4);
        f32x4 o2 = *(const f32x4*)(os + 8);
        f32x4 o3 = *(const f32x4*)(os + 12);
        f32x4 o4 = *(const f32x4*)(os + 16);
        f32x4 o5 = *(const f32x4*)(os + 20);
        f32x4 o6 = *(const f32x4*)(os + 24);
        float tors[6] = {o0[0], o0[1], o0[2], o0[3], o1[0], o1[1]};
        float j0[11] = {o1[2], o2[0], o2[2], o3[0], o3[2], o4[0], o4[2], o5[0], o5[2], o6[0], o6[2]};
        float j1[11] = {o1[3], o2[1], o2[3], o3[1], o3[3], o4[1], o4[3], o5[1], o5[3], o6[1], o6[3]};

        float y0 = b_in_t[fg * 2], y1 = b_in_t[fg * 2 + 1];
        #pragma unroll
        for (int ff = 0; ff < 6; ++ff) {
            y0 = __builtin_fmaf(tors[ff], w_in_t[ff * DD + fg * 2], y0);
            y1 = __builtin_fmaf(tors[ff], w_in_t[ff * DD + fg * 2 + 1], y1);
        }
        bf16x2 t;
        t[0] = (__bf16)tanh_fast(y0); t[1] = (__bf16)tanh_fast(y1);
        *(bf16x2*)(&X[(0 * EPB + ee) * 128 + ((fg * 4) ^ eswz)]) = t;

        const float wj0a = w_in_j[fg * 2], wj0b = w_in_j[fg * 2 + 1];
        const float wj1a = w_in_j[DD + fg * 2], wj1b = w_in_j[DD + fg * 2 + 1];
        const float bja = b_in_j[fg * 2], bjb = b_in_j[fg * 2 + 1];
        #pragma unroll
        for (int n = 1; n < NN; ++n) {
            float ya = __builtin_fmaf(j1[n-1], wj1a, __builtin_fmaf(j0[n-1], wj0a, bja));
            float yb = __builtin_fmaf(j1[n-1], wj1b, __builtin_fmaf(j0[n-1], wj0b, bjb));
            t[0] = (__bf16)tanh_fast(ya); t[1] = (__bf16)tanh_fast(yb);
            *(bf16x2*)(&X[(n * EPB + ee) * 128 + ((fg * 4) ^ eswz)]) = t;
        }
    }

    auto rdfrag = [&](const unsigned char* buf, int n, int ks) {
        return *(const bf16x8*)(buf + (n * EPB + el) * 128 + ((ks * 64 + kg * 16) ^ swz));
    };
    auto ldws = [&](int slot) {
        return *(const bf16x8*)(wsb + ((size_t)slot * 64 + l) * 8);
    };

    f32x4 acc[NN];

    auto gcn_read = [&](const unsigned char* src, int slotbase) {
        bf16x8 wf0 = ldws(slotbase + w * 2 + 0);
        bf16x8 wf1 = ldws(slotbase + w * 2 + 1);
        #pragma unroll
        for (int n = 0; n < NN; ++n) {
            bf16x8 x0 = rdfrag(src, n, 0);
            bf16x8 x1 = rdfrag(src, n, 1);
            f32x4 a = {0.f, 0.f, 0.f, 0.f};
            a = MFMA(wf0, x0, a);
            a = MFMA(wf1, x1, a);
            acc[n] = a;
        }
    };
    auto gcn_write = [&](unsigned char* dst, const float* bias) {
        f32x4 bv = *(const f32x4*)(bias + w * 16 + kg * 4);
        #pragma unroll
        for (int n = 0; n < NN; ++n) {
            f32x4 y = bv;
            #pragma unroll
            for (int j = AC_OFF[n]; j < AC_OFF[n + 1]; ++j) {
                const float a = ac[j];
                #pragma unroll
                for (int r = 0; r < 4; ++r) y[r] = __builtin_fmaf(a, acc[AC_M[j]][r], y[r]);
            }
            bf16x4 o;
            #pragma unroll
            for (int r = 0; r < 4; ++r) o[r] = (__bf16)tanh_fast(y[r]);
            *(bf16x4*)(dst + (n * EPB + el) * 128 + (((w * 16 + kg * 4) * 2) ^ swz)) = o;
        }
    };

    __syncthreads();                       // B1: X = x ready
    // interval 1: both branches read X; p writes fresh XP
    if (isP) { gcn_read(X, 0);  gcn_write(XP, b_gp1); }   // xp1 -> XP
    else     { gcn_read(X, 16); }                          // acc = x @ Wgv1
    __syncthreads();                       // B2: X fully read; XP visible
    // interval 2: v writes X in place; p reads XP
    if (isP) { gcn_read(XP, 8); }                          // acc = xp1 @ Wgp2
    else     { gcn_write(X, b_gv1); }                      // xv1 -> X
    __syncthreads();                       // B3
    // interval 3: p writes XP in place; v reads X
    if (isP) { gcn_write(XP, b_gp2); }                     // xp2 -> XP
    else     { gcn_read(X, 24); }                          // acc = xv1 @ Wgv2
    __syncthreads();                       // B4
    // interval 4: v writes X in place; p runs policy head on XP
    if (!isP) {
        gcn_write(X, b_gv2);                               // xv2 -> X
    } else {
        f32x4 bp  = *(const f32x4*)(b_pol1 + w * 16 + kg * 4);
        f32x4 wp2 = *(const f32x4*)(w_pol2 + w * 16 + kg * 4);
        bf16x8 pf0 = ldws(32 + w * 2 + 0);
        bf16x8 pf1 = ldws(32 + w * 2 + 1);
        #pragma unroll
        for (int nj = 0; nj < 11; ++nj) {
            bf16x8 x0 = rdfrag(XP, nj + 1, 0);
            bf16x8 x1 = rdfrag(XP, nj + 1, 1);
            f32x4 a = bp;
            a = MFMA(pf0, x0, a);
            a = MFMA(pf1, x1, a);
            float p = 0.f;
            #pragma unroll
            for (int r = 0; r < 4; ++r) p += tanh_fast(a[r]) * wp2[r];
            p += __shfl_xor(p, 16);
            p += __shfl_xor(p, 32);
            if (kg == 0) polp[w * 176 + nj * 16 + el] = p;
        }
    }
    __syncthreads();                       // B5: X = xv2 ready
    // interval 5: v runs value head on X
    if (!isP) {
        f32x4 a0 = *(const f32x4*)(b_val1 + w * 16 + kg * 4);
        f32x4 a1 = {0.f, 0.f, 0.f, 0.f};
        #pragma unroll 4
        for (int ks = 0; ks < 24; ks += 2) {
            bf16x8 wf0 = ldws(40 + w * 24 + ks);
            bf16x8 wf1 = ldws(40 + w * 24 + ks + 1);
            int n = ks >> 1;
            bf16x8 xf0 = rdfrag(X, n, 0);
            bf16x8 xf1 = rdfrag(X, n, 1);
            a0 = MFMA(wf0, xf0, a0);
            a1 = MFMA(wf1, xf1, a1);
        }
        f32x4 wv2 = *(const f32x4*)(w_val2 + w * 16 + kg * 4);
        float p = 0.f;
        #pragma unroll
        for (int r = 0; r < 4; ++r) p += tanh_fast(a0[r] + a1[r]) * wv2[r];
        p += __shfl_xor(p, 16);
        p += __shfl_xor(p, 32);
        if (kg == 0) valp[w * 16 + el] = p;
    }
    __syncthreads();                       // B6: partials ready

    if (tid < 176) {
        int e2 = tid / 11, nj = tid - e2 * 11;
        out[(size_t)b0 * 11 + tid] =
            polp[nj * 16 + e2] + polp[176 + nj * 16 + e2] +
            polp[352 + nj * 16 + e2] + polp[528 + nj * 16 + e2] + b_pol2[0];
    }
    if (tid >= 192 && tid < 192 + EPB) {
        int e2 = tid - 192;
        out[(size_t)NB * 11 + b0 + e2] =
            valp[e2] + valp[16 + e2] + valp[32 + e2] + valp[48 + e2] + b_val2[0];
    }
}

extern "C" void kernel_launch(void* const* d_in, const int* in_sizes, int n_in,
                              void* d_out, int out_size, void* d_ws, size_t ws_size,
                              hipStream_t stream) {
    (void)in_sizes; (void)n_in; (void)out_size; (void)ws_size;
    const float** p = (const float**)d_in;
    __bf16* wsb = (__bf16*)d_ws;
    hipLaunchKernelGGL(prep_weights, dim3(34), dim3(256), 0, stream,
        p[6], p[8], p[10], p[12], p[14], p[18], wsb);
    hipLaunchKernelGGL(nervenet_mfma, dim3(NB / EPB), dim3(512), 0, stream,
        p[0], p[1], p[2], p[3], p[4], p[5],
        p[7], p[9], p[11], p[13],
        p[15], p[16], p[17],
        p[19], p[20], p[21],
        wsb, (float*)d_out);
}

// Round 5
// 61.167 us; speedup vs baseline: 15.2592x; 1.1097x over previous
//
#include <hip/hip_runtime.h>

#define NB 32768
#define NN 12
#define DD 64
#define OBSD 28
#define EPB 16            // batch elements per block (one MFMA N-tile)
#define NSLOT 136         // weight-fragment slots in d_ws

typedef __bf16 bf16x8 __attribute__((ext_vector_type(8)));
typedef __bf16 bf16x4 __attribute__((ext_vector_type(4)));
typedef __bf16 bf16x2 __attribute__((ext_vector_type(2)));
typedef float  f32x4  __attribute__((ext_vector_type(4)));

#define MFMA(a, b, c) __builtin_amdgcn_mfma_f32_16x16x32_bf16((a), (b), (c), 0, 0, 0)

__device__ __forceinline__ float tanh_fast(float x) {
    // tanh(x) = 1 - 2/(e^{2x}+1);  e^{2x} = 2^(x*2/ln2).  3 full-rate + 2 trans ops.
    float e = __builtin_amdgcn_exp2f(x * 2.885390081777927f);
    float r = __builtin_amdgcn_rcpf(e + 1.f);
    return __builtin_fmaf(-2.f, r, 1.f);
}

// adjacency sparsity (12 nodes, 11 edges + self loops = 34 nonzeros), grouped by output node
static constexpr int AC_OFF[13] = {0,5,8,11,13,16,19,21,24,27,29,32,34};
static constexpr int AC_M[34] = {0,1,4,7,10, 0,1,2, 1,2,3, 2,3, 0,4,5, 4,5,6, 5,6, 0,7,8, 7,8,9, 8,9, 0,10,11, 10,11};
static constexpr int AC_N[34] = {0,0,0,0,0, 1,1,1, 2,2,2, 3,3, 4,4,4, 5,5,5, 6,6, 7,7,7, 8,8,8, 9,9, 10,10,10, 11,11};

// ---------------------------------------------------------------------------
// prep: pack W^T into MFMA A-fragment layout, bf16, into d_ws.
// slot map: 0..31 gcn {gp1,gp2,gv1,gv2}: mat*8 + w*2 + ks
//           32..39 pol1: 32 + w*2 + ks
//           40..135 val1: 40 + w*24 + ks   (K=768 -> 24 ksteps)
// per (slot, lane): 8 bf16 = A[w*16 + (l&15)][ks*32 + (l>>4)*8 + i] = W[k][dout]
// ---------------------------------------------------------------------------
__global__ __launch_bounds__(256) void prep_weights(
    const float* __restrict__ gp1, const float* __restrict__ gp2,
    const float* __restrict__ gv1, const float* __restrict__ gv2,
    const float* __restrict__ pol1, const float* __restrict__ val1,
    __bf16* __restrict__ wsb)
{
    int gid = blockIdx.x * blockDim.x + threadIdx.x;
    if (gid >= NSLOT * 64) return;
    int slot = gid >> 6, l = gid & 63;
    const float* W; int w, ks;
    if (slot < 32) {
        int m = slot >> 3;
        W = (m == 0) ? gp1 : (m == 1) ? gp2 : (m == 2) ? gv1 : gv2;
        w = (slot >> 1) & 3; ks = slot & 1;
    } else if (slot < 40) {
        W = pol1; w = (slot - 32) >> 1; ks = slot & 1;
    } else {
        int idx = slot - 40; W = val1; w = idx / 24; ks = idx % 24;
    }
    int dout = w * 16 + (l & 15);
    int k0 = ks * 32 + (l >> 4) * 8;
    bf16x8 v;
    #pragma unroll
    for (int i = 0; i < 8; ++i) v[i] = (__bf16)W[(size_t)(k0 + i) * 64 + dout];
    *(bf16x8*)(wsb + (size_t)gid * 8) = v;
}

// ---------------------------------------------------------------------------
// main kernel: 512 threads = 8 waves. Waves 0-3 = policy-branch tiles, 4-7 =
// value-branch tiles. Balanced schedule: every barrier interval has BOTH
// groups doing identical-shape work (R|R, W|W, heads split 7/7 units).
// LDS = 2*24576 + 2816 + 256 = 52224 B -> 3 blocks/CU.
// ---------------------------------------------------------------------------
__global__ __launch_bounds__(512, 6) void nervenet_mfma(
    const float* __restrict__ obs, const float* __restrict__ adjn,
    const float* __restrict__ w_in_t, const float* __restrict__ b_in_t,
    const float* __restrict__ w_in_j, const float* __restrict__ b_in_j,
    const float* __restrict__ b_gp1, const float* __restrict__ b_gp2,
    const float* __restrict__ b_gv1, const float* __restrict__ b_gv2,
    const float* __restrict__ b_pol1, const float* __restrict__ w_pol2, const float* __restrict__ b_pol2,
    const float* __restrict__ b_val1, const float* __restrict__ w_val2, const float* __restrict__ b_val2,
    const __bf16* __restrict__ wsb, float* __restrict__ out)
{
    // [node][el][feat] bf16, rows 128 B, XOR-swizzled by (el&7)<<4
    __shared__ unsigned char X [NN * EPB * DD * 2];   // 24576: x -> xv1 -> xv2 (in place)
    __shared__ unsigned char XP[NN * EPB * DD * 2];   // 24576: xp1 -> xp2 (in place)
    __shared__ float polp[4 * 11 * EPB];              // 2816 policy partials
    __shared__ float valp[4 * EPB];                   // 256  value partials

    const int tid = threadIdx.x;
    const int l   = tid & 63;
    const int el  = l & 15;
    const int kg  = l >> 4;
    const int wv  = tid >> 6;        // 0..7
    const int w   = wv & 3;          // out-feature tile within branch
    const bool isP = wv < 4;
    const int b0  = blockIdx.x * EPB;
    const int swz = (el & 7) << 4;

    // adjacency coefficients: literal indices + uniform pointer -> scalar loads
    float ac[34];
    #pragma unroll
    for (int i = 0; i < 34; ++i) ac[i] = adjn[AC_N[i] * 12 + AC_M[i]];

    // ---- embed: all 8 waves, each thread 2 feats x 12 nodes, obs direct from global ----
    {
        const int ee = tid & 15, fg = tid >> 4;       // fg 0..31 -> feats fg*2, fg*2+1
        const int eswz = (ee & 7) << 4;
        const float* os = obs + (size_t)(b0 + ee) * OBSD;   // 112B rows, 16B-aligned
        f32x4 o0 = *(const f32x4*)(os);
        f32x4 o1 = *(const f32x4*)(os + 4);
        f32x4 o2 = *(const f32x4*)(os + 8);
        f32x4 o3 = *(const f32x4*)(os + 12);
        f32x4 o4 = *(const f32x4*)(os + 16);
        f32x4 o5 = *(const f32x4*)(os + 20);
        f32x4 o6 = *(const f32x4*)(os + 24);
        float tors[6] = {o0[0], o0[1], o0[2], o0[3], o1[0], o1[1]};
        float j0[11] = {o1[2], o2[0], o2[2], o3[0], o3[2], o4[0], o4[2], o5[0], o5[2], o6[0], o6[2]};
        float j1[11] = {o1[3], o2[1], o2[3], o3[1], o3[3], o4[1], o4[3], o5[1], o5[3], o6[1], o6[3]};

        float y0 = b_in_t[fg * 2], y1 = b_in_t[fg * 2 + 1];
        #pragma unroll
        for (int ff = 0; ff < 6; ++ff) {
            y0 = __builtin_fmaf(tors[ff], w_in_t[ff * DD + fg * 2], y0);
            y1 = __builtin_fmaf(tors[ff], w_in_t[ff * DD + fg * 2 + 1], y1);
        }
        bf16x2 t;
        t[0] = (__bf16)tanh_fast(y0); t[1] = (__bf16)tanh_fast(y1);
        *(bf16x2*)(&X[(0 * EPB + ee) * 128 + ((fg * 4) ^ eswz)]) = t;

        const float wj0a = w_in_j[fg * 2], wj0b = w_in_j[fg * 2 + 1];
        const float wj1a = w_in_j[DD + fg * 2], wj1b = w_in_j[DD + fg * 2 + 1];
        const float bja = b_in_j[fg * 2], bjb = b_in_j[fg * 2 + 1];
        #pragma unroll
        for (int n = 1; n < NN; ++n) {
            float ya = __builtin_fmaf(j1[n-1], wj1a, __builtin_fmaf(j0[n-1], wj0a, bja));
            float yb = __builtin_fmaf(j1[n-1], wj1b, __builtin_fmaf(j0[n-1], wj0b, bjb));
            t[0] = (__bf16)tanh_fast(ya); t[1] = (__bf16)tanh_fast(yb);
            *(bf16x2*)(&X[(n * EPB + ee) * 128 + ((fg * 4) ^ eswz)]) = t;
        }
    }

    auto rdfrag = [&](const unsigned char* buf, int n, int ks) {
        return *(const bf16x8*)(buf + (n * EPB + el) * 128 + ((ks * 64 + kg * 16) ^ swz));
    };
    auto ldws = [&](int slot) {
        return *(const bf16x8*)(wsb + ((size_t)slot * 64 + l) * 8);
    };

    f32x4 acc[NN];

    auto gcn_read = [&](const unsigned char* src, int slotbase) {
        bf16x8 wf0 = ldws(slotbase + w * 2 + 0);
        bf16x8 wf1 = ldws(slotbase + w * 2 + 1);
        #pragma unroll
        for (int n = 0; n < NN; ++n) {
            bf16x8 x0 = rdfrag(src, n, 0);
            bf16x8 x1 = rdfrag(src, n, 1);
            f32x4 a = {0.f, 0.f, 0.f, 0.f};
            a = MFMA(wf0, x0, a);
            a = MFMA(wf1, x1, a);
            acc[n] = a;
        }
    };
    auto gcn_write = [&](unsigned char* dst, const float* bias) {
        f32x4 bv = *(const f32x4*)(bias + w * 16 + kg * 4);
        #pragma unroll
        for (int n = 0; n < NN; ++n) {
            f32x4 y = bv;
            #pragma unroll
            for (int j = AC_OFF[n]; j < AC_OFF[n + 1]; ++j) {
                const float a = ac[j];
                #pragma unroll
                for (int r = 0; r < 4; ++r) y[r] = __builtin_fmaf(a, acc[AC_M[j]][r], y[r]);
            }
            bf16x4 o;
            #pragma unroll
            for (int r = 0; r < 4; ++r) o[r] = (__bf16)tanh_fast(y[r]);
            *(bf16x4*)(dst + (n * EPB + el) * 128 + (((w * 16 + kg * 4) * 2) ^ swz)) = o;
        }
    };

    unsigned char* MYBUF = isP ? XP : X;     // wave-uniform select

    __syncthreads();                         // B1: X = x ready
    // R1: both groups read X
    gcn_read(X, isP ? 0 : 16);
    __syncthreads();                         // B2: X fully read
    // W1: p -> XP (fresh), v -> X (in place)
    gcn_write(MYBUF, isP ? b_gp1 : b_gv1);
    __syncthreads();                         // B3: layer-1 outputs visible
    // R2: p reads XP, v reads X
    gcn_read(MYBUF, isP ? 8 : 24);
    __syncthreads();                         // B4: buffers fully read
    // W2: in place
    gcn_write(MYBUF, isP ? b_gp2 : b_gv2);
    __syncthreads();                         // B5: xp2 in XP, xv2 in X

    // ---- heads, balanced: all 8 waves run policy units (0-3: nj 0..6, 4-7: nj 7..10);
    //      waves 4-7 additionally run the value head. (~7 units each)
    {
        f32x4 bp  = *(const f32x4*)(b_pol1 + w * 16 + kg * 4);
        f32x4 wp2 = *(const f32x4*)(w_pol2 + w * 16 + kg * 4);
        bf16x8 pf0 = ldws(32 + w * 2 + 0);
        bf16x8 pf1 = ldws(32 + w * 2 + 1);
        auto pol_unit = [&](int nj) {
            bf16x8 x0 = rdfrag(XP, nj + 1, 0);
            bf16x8 x1 = rdfrag(XP, nj + 1, 1);
            f32x4 a = bp;
            a = MFMA(pf0, x0, a);
            a = MFMA(pf1, x1, a);
            float p = 0.f;
            #pragma unroll
            for (int r = 0; r < 4; ++r) p += tanh_fast(a[r]) * wp2[r];
            p += __shfl_xor(p, 16);
            p += __shfl_xor(p, 32);
            if (kg == 0) polp[w * 176 + nj * 16 + el] = p;
        };
        if (isP) {
            #pragma unroll
            for (int nj = 0; nj < 7; ++nj) pol_unit(nj);
        } else {
            #pragma unroll
            for (int nj = 7; nj < 11; ++nj) pol_unit(nj);
            // value head on X (= xv2)
            f32x4 a0 = *(const f32x4*)(b_val1 + w * 16 + kg * 4);
            f32x4 a1 = {0.f, 0.f, 0.f, 0.f};
            #pragma unroll 4
            for (int ks = 0; ks < 24; ks += 2) {
                bf16x8 wf0 = ldws(40 + w * 24 + ks);
                bf16x8 wf1 = ldws(40 + w * 24 + ks + 1);
                int n = ks >> 1;
                bf16x8 xf0 = rdfrag(X, n, 0);
                bf16x8 xf1 = rdfrag(X, n, 1);
                a0 = MFMA(wf0, xf0, a0);
                a1 = MFMA(wf1, xf1, a1);
            }
            f32x4 wv2 = *(const f32x4*)(w_val2 + w * 16 + kg * 4);
            float p = 0.f;
            #pragma unroll
            for (int r = 0; r < 4; ++r) p += tanh_fast(a0[r] + a1[r]) * wv2[r];
            p += __shfl_xor(p, 16);
            p += __shfl_xor(p, 32);
            if (kg == 0) valp[w * 16 + el] = p;
        }
    }
    __syncthreads();                         // B6: partials ready

    if (tid < 176) {
        int e2 = tid / 11, nj = tid - e2 * 11;
        out[(size_t)b0 * 11 + tid] =
            polp[nj * 16 + e2] + polp[176 + nj * 16 + e2] +
            polp[352 + nj * 16 + e2] + polp[528 + nj * 16 + e2] + b_pol2[0];
    }
    if (tid >= 192 && tid < 192 + EPB) {
        int e2 = tid - 192;
        out[(size_t)NB * 11 + b0 + e2] =
            valp[e2] + valp[16 + e2] + valp[32 + e2] + valp[48 + e2] + b_val2[0];
    }
}

extern "C" void kernel_launch(void* const* d_in, const int* in_sizes, int n_in,
                              void* d_out, int out_size, void* d_ws, size_t ws_size,
                              hipStream_t stream) {
    (void)in_sizes; (void)n_in; (void)out_size; (void)ws_size;
    const float** p = (const float**)d_in;
    __bf16* wsb = (__bf16*)d_ws;
    hipLaunchKernelGGL(prep_weights, dim3(34), dim3(256), 0, stream,
        p[6], p[8], p[10], p[12], p[14], p[18], wsb);
    hipLaunchKernelGGL(nervenet_mfma, dim3(NB / EPB), dim3(512), 0, stream,
        p[0], p[1], p[2], p[3], p[4], p[5],
        p[7], p[9], p[11], p[13],
        p[15], p[16], p[17],
        p[19], p[20], p[21],
        wsb, (float*)d_out);
}